// Round 2
// baseline (1830.993 us; speedup 1.0000x reference)
//
#include <hip/hip_runtime.h>
#include <hip/hip_bf16.h>
#include <stdint.h>

#define TT 256

typedef __attribute__((ext_vector_type(4))) float f32x4;
typedef __attribute__((ext_vector_type(8))) short s16x8;

#define DEV static __device__ __forceinline__

DEV short f2bf(float f){
  union{float f; uint32_t u;} v; v.f = f;
  uint32_t r = v.u + 0x7fffu + ((v.u>>16)&1u);
  return (short)(r>>16);
}
DEV float bf2f(uint32_t u16){
  union{uint32_t u; float f;} v; v.u = u16<<16; return v.f;
}
DEV uint32_t pk2(float a, float b){
  return (uint32_t)(uint16_t)f2bf(a) | ((uint32_t)(uint16_t)f2bf(b)<<16);
}
DEV float sigm(float x){ return 1.f/(1.f + __expf(-x)); }
DEV float tanh_f(float x){ float e = __expf(2.f*x); return 1.f - 2.f/(e+1.f); }
DEV f32x4 MFMA(s16x8 a, s16x8 b, f32x4 c){
  return __builtin_amdgcn_mfma_f32_16x16x32_bf16(a, b, c, 0, 0, 0);
}

// ---------------- LayerNorm over D_IN=6 (full batch, 6.3 MB) ----------------
__global__ __launch_bounds__(256) void ln_kernel(
    const float* __restrict__ x, const float* __restrict__ g,
    const float* __restrict__ bsh, float* __restrict__ xn)
{
  int row = blockIdx.x*256 + threadIdx.x;        // B*T rows
  const float* p = x + (size_t)row*6;
  float v[6]; float mu = 0.f, var = 0.f;
  #pragma unroll
  for (int d=0; d<6; ++d){ v[d] = p[d]; mu += v[d]; }
  mu *= (1.f/6.f);
  #pragma unroll
  for (int d=0; d<6; ++d){ float dd = v[d]-mu; var += dd*dd; }
  float r = rsqrtf(var*(1.f/6.f) + 1e-5f);
  float* q = xn + (size_t)row*6;
  #pragma unroll
  for (int d=0; d<6; ++d) q[d] = (v[d]-mu)*r*g[d] + bsh[d];
}

// ---------------- Wih1 -> B-fragment layout (bf16) ----------------
// Wih1f[dir][ntg(32)][kt(8)][lane(64)][8];  n = ntg*16 + (lane&15), k = (lane>>4)*8+j
__global__ __launch_bounds__(256) void prep_wih1(
    const float* __restrict__ Wih1, uint16_t* __restrict__ Wih1f)
{
  int tid = blockIdx.x*256 + threadIdx.x;   // 32768 total
  int l = tid & 63, kt = (tid>>6)&7, ntg = (tid>>9)&31, dir = (tid>>14)&1;
  int lm = l&15, lk = l>>4;
  int n = ntg*16 + lm;
  const float* p = Wih1 + ((size_t)(dir*512 + n))*256 + kt*32 + lk*8;
  s16x8 o;
  #pragma unroll
  for (int j=0; j<8; ++j) o[j] = f2bf(p[j]);
  *(s16x8*)(Wih1f + (size_t)tid*8) = o;
}

// ---------------- BiLSTM layer 0 (D_IN=6 -> H=128/dir), 8 waves ----------------
__global__ __launch_bounds__(512,2) void lstm0_kernel(
    const float* __restrict__ xn, const float* __restrict__ Wih0,
    const float* __restrict__ Whh0, const float* __restrict__ bih0,
    const float* __restrict__ bhh0, uint16_t* __restrict__ h0,
    int nb, int BR, int b_off)
{
  const int dir = blockIdx.x / nb, bg = blockIdx.x % nb;
  const int tid = threadIdx.x, w = tid>>6, l = tid&63;
  const int lm = l&15, lk = l>>4;
  const int gb = b_off + bg*8;

  __shared__ short hbuf[16*128];     // bf16, XOR-swizzled rows (rows 8..15 stay 0)
  __shared__ short xnbf[TT*8*8];     // [t][r][8] bf16 (K=6 padded to 8), 32 KB

  for (int i=tid; i<16*128; i+=512) hbuf[i] = 0;
  #pragma unroll
  for (int it=0; it<4; ++it){
    int pr = it*512 + tid;           // (r,t)
    int r = pr >> 8, t = pr & 255;
    const float* px = xn + ((size_t)(gb+r)*TT + t)*6;
    s16x8 vv;
    #pragma unroll
    for (int d=0; d<6; ++d) vv[d] = f2bf(px[d]);
    vv[6] = 0; vv[7] = 0;
    *(s16x8*)&xnbf[(t*8 + r)*8] = vv;
  }

  // wave w owns gate cols c = w*16 + lm, gates G=0..3 at n = G*128 + c
  const int c = w*16 + lm;
  s16x8 bw[4][4], bx[4];
  float biasc[4];
  #pragma unroll
  for (int G=0; G<4; ++G){
    const int n = G*128 + c;
    biasc[G] = bih0[dir*512+n] + bhh0[dir*512+n];
    #pragma unroll
    for (int kt=0; kt<4; ++kt){
      const float* p = Whh0 + ((size_t)(dir*512+n)*128 + kt*32 + lk*8);
      s16x8 tmp;
      #pragma unroll
      for (int j=0; j<8; ++j) tmp[j] = f2bf(p[j]);
      bw[G][kt] = tmp;
    }
    s16x8 tx;
    #pragma unroll
    for (int j=0; j<8; ++j){
      int k = lk*8 + j;
      tx[j] = (k<6) ? f2bf(Wih0[(size_t)(dir*512+n)*6 + k]) : (short)0;
    }
    bx[G] = tx;
  }

  const int jr = (l<32) ? 0 : 2;
  const int r0 = ((l>>4)&1)*4 + jr;   // lanes: [0,16)->0, [16,32)->4, [32,48)->2, [48,64)->6
  float cst[2] = {0.f, 0.f};
  __syncthreads();

  for (int t=0; t<TT; ++t){
    const int tt = dir ? (TT-1-t) : t;
    s16x8 ah[4];
    #pragma unroll
    for (int kt=0; kt<4; ++kt){
      int off = lm*256 + ((kt*64 + lk*16) ^ ((lm&7)<<4));
      ah[kt] = *(const s16x8*)((const char*)hbuf + off);
    }
    s16x8 ax = {0,0,0,0,0,0,0,0};
    if (l < 8) ax = *(const s16x8*)&xnbf[(tt*8 + l)*8];

    f32x4 acc[4];
    #pragma unroll
    for (int G=0; G<4; ++G){
      f32x4 a = {0.f,0.f,0.f,0.f};
      #pragma unroll
      for (int kt=0; kt<4; ++kt) a = MFMA(ah[kt], bw[G][kt], a);
      a = MFMA(ax, bx[G], a);
      acc[G] = a;
    }

    float g0[4], g1[4];
    #pragma unroll
    for (int G=0; G<4; ++G){
      float o2 = __shfl(acc[G][2], l & 31);
      float o3 = __shfl(acc[G][3], l & 31);
      g0[G] = ((l<32) ? acc[G][0] : o2) + biasc[G];
      g1[G] = ((l<32) ? acc[G][1] : o3) + biasc[G];
    }
    float hv[2];
    {
      float cc = sigm(g0[1])*cst[0] + sigm(g0[0])*tanh_f(g0[2]);
      cst[0] = cc; hv[0] = sigm(g0[3])*tanh_f(cc);
      cc = sigm(g1[1])*cst[1] + sigm(g1[0])*tanh_f(g1[2]);
      cst[1] = cc; hv[1] = sigm(g1[3])*tanh_f(cc);
    }

    __syncthreads();   // all A-frag reads done before overwriting hbuf
    #pragma unroll
    for (int q=0; q<2; ++q){
      int r = r0 + q;
      short hb = f2bf(hv[q]);
      *(short*)((char*)hbuf + (r*256 + ((c*2) ^ ((r&7)<<4)))) = hb;
      h0[((size_t)tt*BR + bg*8 + r)*256 + dir*128 + c] = (uint16_t)hb;
    }
    __syncthreads();
  }
}

// ---------------- BiLSTM layer 1 (256 -> 128/dir), fused xp, 8 waves ----------------
__global__ __launch_bounds__(512,2) void lstm1_kernel(
    const uint16_t* __restrict__ h0, const uint16_t* __restrict__ Wih1f,
    const float* __restrict__ Whh1, const float* __restrict__ bih1,
    const float* __restrict__ bhh1, uint16_t* __restrict__ h1,
    int nb, int BR)
{
  const int dir = blockIdx.x / nb, bg = blockIdx.x % nb;
  const int tid = threadIdx.x, w = tid>>6, l = tid&63;
  const int lm = l&15, lk = l>>4;

  __shared__ short hbuf[16*128];
  __shared__ short abuf[64*256];    // chunk A: [64 rows][256] bf16, swizzled, 32 KB

  for (int i=tid; i<16*128; i+=512) hbuf[i] = 0;

  const int c = w*16 + lm;
  s16x8 bw[4][4];
  float biasv[4];
  #pragma unroll
  for (int G=0; G<4; ++G){
    const int n = G*128 + c;
    biasv[G] = bih1[dir*512+n] + bhh1[dir*512+n];
    #pragma unroll
    for (int kt=0; kt<4; ++kt){
      const float* p = Whh1 + ((size_t)(dir*512+n)*128 + kt*32 + lk*8);
      s16x8 tmp;
      #pragma unroll
      for (int j=0; j<8; ++j) tmp[j] = f2bf(p[j]);
      bw[G][kt] = tmp;
    }
  }

  const int jr = (l<32) ? 0 : 2;
  const int r0 = ((l>>4)&1)*4 + jr;
  float cst[2] = {0.f,0.f};
  uint32_t xpk[4][4][2];   // packed bf16 xp per (G, mt)
  __syncthreads();

  for (int ch=0; ch<32; ++ch){
    // ---- stage A chunk: rows m = s*8 + b ----
    #pragma unroll
    for (int it=0; it<4; ++it){
      int sid = it*512 + tid;
      int row = sid >> 5, sl = sid & 31;
      int s = row >> 3, b = row & 7;
      int tg = dir ? (TT-1-(ch*8+s)) : (ch*8+s);
      s16x8 v = *(const s16x8*)(h0 + ((size_t)tg*BR + bg*8 + b)*256 + sl*8);
      *(s16x8*)((char*)abuf + row*512 + ((sl ^ (row&7))<<4)) = v;
    }
    __syncthreads();

    // ---- phase A: xp for 8 steps ----
    #pragma unroll
    for (int mp=0; mp<2; ++mp){
      s16x8 afr[2][8];
      #pragma unroll
      for (int mi=0; mi<2; ++mi){
        #pragma unroll
        for (int kt=0; kt<8; ++kt){
          int row = (mp*2+mi)*16 + lm;
          afr[mi][kt] = *(const s16x8*)((const char*)abuf + row*512 + (((kt*4+lk) ^ (row&7))<<4));
        }
      }
      #pragma unroll
      for (int G=0; G<4; ++G){
        const int ntg = G*8 + w;
        f32x4 a0 = {biasv[G],biasv[G],biasv[G],biasv[G]};
        f32x4 a1 = a0;
        #pragma unroll
        for (int kt=0; kt<8; ++kt){
          s16x8 bfr = *(const s16x8*)(Wih1f + (((size_t)(dir*32+ntg)*8 + kt)*64 + l)*8);
          a0 = MFMA(afr[0][kt], bfr, a0);
          a1 = MFMA(afr[1][kt], bfr, a1);
        }
        xpk[G][mp*2  ][0] = pk2(a0[0],a0[1]); xpk[G][mp*2  ][1] = pk2(a0[2],a0[3]);
        xpk[G][mp*2+1][0] = pk2(a1[0],a1[1]); xpk[G][mp*2+1][1] = pk2(a1[2],a1[3]);
      }
    }

    // ---- phase B: 8 recurrent steps ----
    #pragma unroll
    for (int s=0; s<8; ++s){
      const int mt = s>>1;
      const bool odd = (s&1) != 0;
      const int tg = dir ? (TT-1-(ch*8+s)) : (ch*8+s);

      f32x4 acc[4];
      #pragma unroll
      for (int G=0; G<4; ++G){
        uint32_t p0 = xpk[G][mt][0], p1 = xpk[G][mt][1];
        if (odd){
          p0 = (uint32_t)__shfl((int)p0, (l+32)&63);
          p1 = (uint32_t)__shfl((int)p1, (l+32)&63);
        }
        f32x4 a;
        a[0]=bf2f(p0&0xffffu); a[1]=bf2f(p0>>16);
        a[2]=bf2f(p1&0xffffu); a[3]=bf2f(p1>>16);
        acc[G] = a;
      }

      s16x8 ah[4];
      #pragma unroll
      for (int kt=0; kt<4; ++kt){
        int off = lm*256 + ((kt*64 + lk*16) ^ ((lm&7)<<4));
        ah[kt] = *(const s16x8*)((const char*)hbuf + off);
      }
      #pragma unroll
      for (int G=0; G<4; ++G){
        #pragma unroll
        for (int kt=0; kt<4; ++kt)
          acc[G] = MFMA(ah[kt], bw[G][kt], acc[G]);
      }

      float g0[4], g1[4];
      #pragma unroll
      for (int G=0; G<4; ++G){
        float o2 = __shfl(acc[G][2], l & 31);
        float o3 = __shfl(acc[G][3], l & 31);
        g0[G] = (l<32) ? acc[G][0] : o2;
        g1[G] = (l<32) ? acc[G][1] : o3;
      }
      float hv[2];
      float cc = sigm(g0[1])*cst[0] + sigm(g0[0])*tanh_f(g0[2]);
      cst[0] = cc; hv[0] = sigm(g0[3])*tanh_f(cc);
      cc = sigm(g1[1])*cst[1] + sigm(g1[0])*tanh_f(g1[2]);
      cst[1] = cc; hv[1] = sigm(g1[3])*tanh_f(cc);

      __syncthreads();
      #pragma unroll
      for (int q=0; q<2; ++q){
        int r = r0 + q;
        short hb = f2bf(hv[q]);
        *(short*)((char*)hbuf + (r*256 + ((c*2) ^ ((r&7)<<4)))) = hb;
        h1[((size_t)tg*BR + bg*8 + r)*256 + dir*128 + c] = (uint16_t)hb;
      }
      __syncthreads();
    }
  }
}

// ---------------- attention scores ----------------
__global__ __launch_bounds__(256,2) void scores_kernel(
    const uint16_t* __restrict__ h1, const float* __restrict__ Wa1,
    const float* __restrict__ ba1, const float* __restrict__ Wa2,
    const float* __restrict__ ba2, float* __restrict__ scores,
    int nbb, int BR)
{
  const int bx = blockIdx.x;
  const int t = bx / nbb, bb = (bx - t*nbb) * 64;
  const int tid = threadIdx.x, w = tid>>6, l = tid&63;
  const int lm = l&15, lk = l>>4;
  __shared__ short abuf[64*256];
  __shared__ float scred[4][64];

  #pragma unroll
  for (int it=0; it<8; ++it){
    int sid = it*256 + tid, row = sid>>5, sl = sid&31;
    s16x8 v = *(const s16x8*)(h1 + ((size_t)t*BR + bb + row)*256 + sl*8);
    *(s16x8*)((char*)abuf + row*512 + ((sl ^ (row&7))<<4)) = v;
  }

  s16x8 bwa[2][8]; float b1v[2], wa2v[2];
  #pragma unroll
  for (int nt=0; nt<2; ++nt){
    int n = w*32 + nt*16 + lm;
    b1v[nt] = ba1[n]; wa2v[nt] = Wa2[n];
    #pragma unroll
    for (int kt=0; kt<8; ++kt){
      const float* p = Wa1 + (size_t)n*256 + kt*32 + lk*8;
      s16x8 tmp;
      #pragma unroll
      for (int j=0; j<8; ++j) tmp[j] = f2bf(p[j]);
      bwa[nt][kt] = tmp;
    }
  }
  __syncthreads();

  #pragma unroll
  for (int mt=0; mt<4; ++mt){
    f32x4 a0 = {b1v[0],b1v[0],b1v[0],b1v[0]};
    f32x4 a1 = {b1v[1],b1v[1],b1v[1],b1v[1]};
    #pragma unroll
    for (int kt=0; kt<8; ++kt){
      int row = mt*16 + lm;
      s16x8 af = *(const s16x8*)((const char*)abuf + row*512 + (((kt*4+lk) ^ (row&7))<<4));
      a0 = MFMA(af, bwa[0][kt], a0);
      a1 = MFMA(af, bwa[1][kt], a1);
    }
    #pragma unroll
    for (int j=0; j<4; ++j){
      float pj = tanh_f(a0[j])*wa2v[0] + tanh_f(a1[j])*wa2v[1];
      #pragma unroll
      for (int m=1; m<16; m<<=1) pj += __shfl_xor(pj, m);
      if (lm == 0) scred[w][mt*16 + lk*4 + j] = pj;
    }
  }
  __syncthreads();
  if (tid < 64){
    float s = scred[0][tid]+scred[1][tid]+scred[2][tid]+scred[3][tid] + ba2[0];
    scores[(size_t)(bb+tid)*TT + t] = s;
  }
}

// ---------------- softmax over T + context ----------------
__global__ __launch_bounds__(256,2) void ctx_kernel(
    const uint16_t* __restrict__ h1, const float* __restrict__ scores,
    float* __restrict__ context, int BR)
{
  const int b = blockIdx.x, tid = threadIdx.x;
  __shared__ float at[TT];
  __shared__ float red[8];
  float sc = scores[(size_t)b*TT + tid];
  float m = sc;
  #pragma unroll
  for (int d=1; d<64; d<<=1) m = fmaxf(m, __shfl_xor(m, d));
  if ((tid&63)==0) red[tid>>6] = m;
  __syncthreads();
  m = fmaxf(fmaxf(red[0],red[1]), fmaxf(red[2],red[3]));
  float e = __expf(sc - m);
  float s = e;
  #pragma unroll
  for (int d=1; d<64; d<<=1) s += __shfl_xor(s, d);
  if ((tid&63)==0) red[4+(tid>>6)] = s;
  __syncthreads();
  s = red[4]+red[5]+red[6]+red[7];
  at[tid] = e / s;
  __syncthreads();

  float acc = 0.f;
  const uint16_t* hp = h1 + (size_t)b*256 + tid;
  #pragma unroll 4
  for (int t2=0; t2<TT; ++t2) acc += at[t2] * bf2f(hp[(size_t)t2*BR*256]);
  context[(size_t)b*256 + tid] = acc;
}

// ---------------- head ----------------
__global__ __launch_bounds__(128,2) void head_kernel(
    const float* __restrict__ ctx, const float* __restrict__ Wf1,
    const float* __restrict__ bf1, const float* __restrict__ g2,
    const float* __restrict__ b2, const float* __restrict__ Wf2,
    const float* __restrict__ bf2v, float* __restrict__ out, int b_off)
{
  const int b = blockIdx.x, tid = threadIdx.x;
  __shared__ float cx[256];
  __shared__ float zb[128];
  __shared__ float red[4];
  cx[tid]       = ctx[(size_t)b*256 + tid];
  cx[128+tid]   = ctx[(size_t)b*256 + 128 + tid];
  __syncthreads();
  float y = bf1[tid];
  const float* wr = Wf1 + (size_t)tid*256;
  #pragma unroll 8
  for (int k=0; k<256; ++k) y += cx[k]*wr[k];
  float s = y;
  #pragma unroll
  for (int d=1; d<64; d<<=1) s += __shfl_xor(s, d);
  if ((tid&63)==0) red[tid>>6] = s;
  __syncthreads();
  float mu = (red[0]+red[1])*(1.f/128.f);
  float dv = y - mu;
  float q = dv*dv;
  #pragma unroll
  for (int d=1; d<64; d<<=1) q += __shfl_xor(q, d);
  if ((tid&63)==0) red[2+(tid>>6)] = q;
  __syncthreads();
  float var = (red[2]+red[3])*(1.f/128.f);
  float z = dv*rsqrtf(var + 1e-5f)*g2[tid] + b2[tid];
  z = fmaxf(z, 0.f);
  zb[tid] = z;
  __syncthreads();
  if (tid < 5){
    float o = bf2v[tid];
    const float* wp = Wf2 + (size_t)tid*128;
    for (int k=0; k<128; ++k) o += zb[k]*wp[k];
    out[(size_t)(b_off + b)*5 + tid] = o;
  }
}

extern "C" void kernel_launch(void* const* d_in, const int* in_sizes, int n_in,
                              void* d_out, int out_size, void* d_ws, size_t ws_size,
                              hipStream_t stream)
{
  const float* x    = (const float*)d_in[0];
  const float* ln_g = (const float*)d_in[1];
  const float* ln_b = (const float*)d_in[2];
  const float* Wih0 = (const float*)d_in[3];
  const float* Whh0 = (const float*)d_in[4];
  const float* bih0 = (const float*)d_in[5];
  const float* bhh0 = (const float*)d_in[6];
  const float* Wih1 = (const float*)d_in[7];
  const float* Whh1 = (const float*)d_in[8];
  const float* bih1 = (const float*)d_in[9];
  const float* bhh1 = (const float*)d_in[10];
  const float* Wa1  = (const float*)d_in[11];
  const float* ba1  = (const float*)d_in[12];
  const float* Wa2  = (const float*)d_in[13];
  const float* ba2  = (const float*)d_in[14];
  const float* Wf1  = (const float*)d_in[15];
  const float* bf1  = (const float*)d_in[16];
  const float* ln2g = (const float*)d_in[17];
  const float* ln2b = (const float*)d_in[18];
  const float* Wf2  = (const float*)d_in[19];
  const float* bf2  = (const float*)d_in[20];

  auto align256 = [](size_t v) -> size_t { return (v + 255) & ~(size_t)255; };
  const size_t XN  = align256((size_t)1024*256*6*4);
  const size_t W1S = align256((size_t)2*32*8*64*8*2);

  // pick largest per-round batch BR (<=512 for ws safety) fitting the workspace
  int BR = 512;
  while (BR > 64){
    size_t need = XN + W1S + 2*align256((size_t)TT*BR*256*2)
                          + 2*align256((size_t)BR*256*4);
    if (need <= ws_size) break;
    BR >>= 1;
  }

  char* wsb = (char*)d_ws;
  size_t off = 0;
  auto alloc = [&](size_t bytes) -> void* {
    void* p = wsb + off; off += (bytes + 255) & ~(size_t)255; return p;
  };
  float*    xn     = (float*)alloc((size_t)1024*256*6*sizeof(float));
  uint16_t* W1f    = (uint16_t*)alloc((size_t)2*32*8*64*8*sizeof(uint16_t));
  uint16_t* h0     = (uint16_t*)alloc((size_t)TT*BR*256*sizeof(uint16_t));
  uint16_t* h1     = (uint16_t*)alloc((size_t)TT*BR*256*sizeof(uint16_t));
  float*    scoresP= (float*)alloc((size_t)BR*256*sizeof(float));
  float*    ctxP   = (float*)alloc((size_t)BR*256*sizeof(float));

  ln_kernel <<<1024, 256, 0, stream>>>(x, ln_g, ln_b, xn);
  prep_wih1 <<<128, 256, 0, stream>>>(Wih1, W1f);

  const int nb = BR/8;
  for (int b_off = 0; b_off < 1024; b_off += BR){
    lstm0_kernel  <<<2*nb, 512, 0, stream>>>(xn, Wih0, Whh0, bih0, bhh0, h0, nb, BR, b_off);
    lstm1_kernel  <<<2*nb, 512, 0, stream>>>(h0, W1f, Whh1, bih1, bhh1, h1, nb, BR);
    scores_kernel <<<TT*(BR/64), 256, 0, stream>>>(h1, Wa1, ba1, Wa2, ba2, scoresP, BR/64, BR);
    ctx_kernel    <<<BR, 256, 0, stream>>>(h1, scoresP, ctxP, BR);
    head_kernel   <<<BR, 128, 0, stream>>>(ctxP, Wf1, bf1, ln2g, ln2b, Wf2, bf2,
                                           (float*)d_out, b_off);
  }
}